// Round 1
// baseline (1219.042 us; speedup 1.0000x reference)
//
#include <hip/hip_runtime.h>
#include <math.h>

#define NW 100000
#define NS 10000
#define NE 800000
#define DIM 256
#define NH 4
#define DHD 64
#define DFF 512
#define NEG_SLOPE 0.2f
#define CAP 64   // bucket capacity per word node; deg ~ Poisson(8), P(>64) ~ 0

// ---------------- helpers ----------------
__device__ __forceinline__ float wave_max64(float v) {
#pragma unroll
    for (int m = 32; m; m >>= 1) v = fmaxf(v, __shfl_xor(v, m, 64));
    return v;
}
__device__ __forceinline__ float wave_sum64(float v) {
#pragma unroll
    for (int m = 32; m; m >>= 1) v += __shfl_xor(v, m, 64);
    return v;
}

// ---------------- kernels ----------------

__global__ void zero_count(int* __restrict__ count) {
    int i = blockIdx.x * 256 + threadIdx.x;
    if (i < NW) count[i] = 0;
}

// C[k,h] = sum_d W[k, h*64+d] * A[h,d]   (two problems: blockIdx 0 = src, 1 = dst)
__global__ void compute_C(const float* __restrict__ W_src, const float* __restrict__ attn_l,
                          const float* __restrict__ W_dst, const float* __restrict__ attn_r,
                          float* __restrict__ C_src, float* __restrict__ C_dst) {
    const float* W = blockIdx.x ? W_dst : W_src;
    const float* A = blockIdx.x ? attn_r : attn_l;
    float* C = blockIdx.x ? C_dst : C_src;
    int k = threadIdx.x;  // 0..255
#pragma unroll
    for (int h = 0; h < NH; h++) {
        float s = 0.f;
        for (int d = 0; d < DHD; d++) s += W[k * DIM + h * DHD + d] * A[h * DHD + d];
        C[k * NH + h] = s;
    }
}

// out[n,h] = X[n,:] @ C[:,h]; one wave per row
__global__ __launch_bounds__(256) void rowdot(const float* __restrict__ X,
                                              const float* __restrict__ C,
                                              float* __restrict__ out, int N) {
    int wave = (blockIdx.x * blockDim.x + threadIdx.x) >> 6;
    int lane = threadIdx.x & 63;
    if (wave >= N) return;
    float4 x = ((const float4*)(X + (size_t)wave * DIM))[lane];
    const float4* Cv = (const float4*)C;  // Cv[k] = C[k][0..3]
    float4 c0 = Cv[lane * 4 + 0], c1 = Cv[lane * 4 + 1], c2 = Cv[lane * 4 + 2], c3 = Cv[lane * 4 + 3];
    float p0 = x.x * c0.x + x.y * c1.x + x.z * c2.x + x.w * c3.x;
    float p1 = x.x * c0.y + x.y * c1.y + x.z * c2.y + x.w * c3.y;
    float p2 = x.x * c0.z + x.y * c1.z + x.z * c2.z + x.w * c3.z;
    float p3 = x.x * c0.w + x.y * c1.w + x.z * c2.w + x.w * c3.w;
    p0 = wave_sum64(p0); p1 = wave_sum64(p1); p2 = wave_sum64(p2); p3 = wave_sum64(p3);
    if (lane == 0) {
        out[(size_t)wave * NH + 0] = p0; out[(size_t)wave * NH + 1] = p1;
        out[(size_t)wave * NH + 2] = p2; out[(size_t)wave * NH + 3] = p3;
    }
}

// feat_src = sent @ W_src : [NS,256] x [256,256]; 16 rows/block, 4x4 per thread
__global__ __launch_bounds__(256) void feat_gemm(const float* __restrict__ X,
                                                 const float* __restrict__ W,
                                                 float* __restrict__ out) {
    __shared__ float a[16][DIM];
    int t = threadIdx.x;
    int rg = t >> 6;        // wave id 0..3 (rows rg*4..rg*4+3)
    int lane = t & 63;
    int c0 = lane * 4;
    size_t row0 = (size_t)blockIdx.x * 16;
#pragma unroll 4
    for (int i = 0; i < 16; i++) a[i][t] = X[(row0 + i) * DIM + t];
    __syncthreads();
    float acc[4][4] = {};
    for (int kk = 0; kk < DIM; kk += 4) {
        float af[4][4];
#pragma unroll
        for (int i = 0; i < 4; i++) {
            float4 v = *(const float4*)&a[rg * 4 + i][kk];
            af[i][0] = v.x; af[i][1] = v.y; af[i][2] = v.z; af[i][3] = v.w;
        }
        float wf[4][4];
#pragma unroll
        for (int j2 = 0; j2 < 4; j2++) {
            float4 v = *(const float4*)&W[(size_t)(kk + j2) * DIM + c0];
            wf[j2][0] = v.x; wf[j2][1] = v.y; wf[j2][2] = v.z; wf[j2][3] = v.w;
        }
#pragma unroll
        for (int i = 0; i < 4; i++)
#pragma unroll
            for (int j2 = 0; j2 < 4; j2++)
#pragma unroll
                for (int j = 0; j < 4; j++)
                    acc[i][j] = fmaf(af[i][j2], wf[j2][j], acc[i][j]);
    }
#pragma unroll
    for (int i = 0; i < 4; i++)
#pragma unroll
        for (int j = 0; j < 4; j++)
            out[(row0 + rg * 4 + i) * DIM + c0 + j] = acc[i][j];
}

// histogram + scatter edges into per-dst buckets
__global__ void scatter_edges(const int* __restrict__ src, const int* __restrict__ dst,
                              int* __restrict__ count, int* __restrict__ bucket) {
    int e = blockIdx.x * 256 + threadIdx.x;
    if (e >= NE) return;
    int w = dst[e];
    int pos = atomicAdd(&count[w], 1);
    if (pos < CAP) bucket[(size_t)w * CAP + pos] = src[e];
}

// one wave per word node: softmax over incoming edges + weighted gather of feat_src,
// then elu + residual -> h (written to h_out)
__global__ __launch_bounds__(256) void gat_aggregate(const int* __restrict__ count,
                                                     const int* __restrict__ bucket,
                                                     const float* __restrict__ el,
                                                     const float* __restrict__ er,
                                                     const float* __restrict__ feat_src,
                                                     const float* __restrict__ word,
                                                     const float* __restrict__ gat_bias,
                                                     float* __restrict__ h_out) {
    int node = blockIdx.x * 4 + (threadIdx.x >> 6);
    int lane = threadIdx.x & 63;
    if (node >= NW) return;
    int deg = count[node];
    if (deg > CAP) deg = CAP;

    float er0 = er[(size_t)node * NH + 0];
    float er1 = er[(size_t)node * NH + 1];
    float er2 = er[(size_t)node * NH + 2];
    float er3 = er[(size_t)node * NH + 3];

    int s = 0;
    float e0 = -3.4e38f, e1 = -3.4e38f, e2 = -3.4e38f, e3 = -3.4e38f;
    if (lane < deg) {
        s = bucket[(size_t)node * CAP + lane];
        float v;
        v = el[(size_t)s * NH + 0] + er0; e0 = v > 0.f ? v : NEG_SLOPE * v;
        v = el[(size_t)s * NH + 1] + er1; e1 = v > 0.f ? v : NEG_SLOPE * v;
        v = el[(size_t)s * NH + 2] + er2; e2 = v > 0.f ? v : NEG_SLOPE * v;
        v = el[(size_t)s * NH + 3] + er3; e3 = v > 0.f ? v : NEG_SLOPE * v;
    }
    float m0 = wave_max64(e0), m1 = wave_max64(e1), m2 = wave_max64(e2), m3 = wave_max64(e3);
    float x0 = lane < deg ? expf(e0 - m0) : 0.f;
    float x1 = lane < deg ? expf(e1 - m1) : 0.f;
    float x2 = lane < deg ? expf(e2 - m2) : 0.f;
    float x3 = lane < deg ? expf(e3 - m3) : 0.f;
    float d0 = wave_sum64(x0), d1 = wave_sum64(x1), d2 = wave_sum64(x2), d3 = wave_sum64(x3);
    float a0 = x0 / d0, a1 = x1 / d1, a2 = x2 / d2, a3 = x3 / d3;  // valid on lanes < deg

    int hh = lane >> 4;  // head of this lane's 4 features
    float4 acc = {0.f, 0.f, 0.f, 0.f};
    for (int i = 0; i < deg; i++) {
        int si = __shfl(s, i, 64);
        float b0 = __shfl(a0, i, 64), b1 = __shfl(a1, i, 64);
        float b2 = __shfl(a2, i, 64), b3 = __shfl(a3, i, 64);
        float aa = hh == 0 ? b0 : hh == 1 ? b1 : hh == 2 ? b2 : b3;
        float4 f = ((const float4*)(feat_src + (size_t)si * DIM))[lane];
        acc.x = fmaf(aa, f.x, acc.x);
        acc.y = fmaf(aa, f.y, acc.y);
        acc.z = fmaf(aa, f.z, acc.z);
        acc.w = fmaf(aa, f.w, acc.w);
    }
    float4 bias = ((const float4*)gat_bias)[lane];
    float4 w = ((const float4*)(word + (size_t)node * DIM))[lane];
    float r0 = acc.x + bias.x; r0 = r0 > 0.f ? r0 : (expf(r0) - 1.f);
    float r1 = acc.y + bias.y; r1 = r1 > 0.f ? r1 : (expf(r1) - 1.f);
    float r2 = acc.z + bias.z; r2 = r2 > 0.f ? r2 : (expf(r2) - 1.f);
    float r3 = acc.w + bias.w; r3 = r3 > 0.f ? r3 : (expf(r3) - 1.f);
    float4 o;
    o.x = w.x + r0; o.y = w.y + r1; o.z = w.z + r2; o.w = w.w + r3;
    ((float4*)(h_out + (size_t)node * DIM))[lane] = o;
}

// out = relu(h@w1+b1)@w2 + b2 ; h and out may alias (block reads own rows first)
__global__ __launch_bounds__(256) void ffn_kernel(const float* h,
                                                  const float* __restrict__ w1,
                                                  const float* __restrict__ b1,
                                                  const float* __restrict__ w2,
                                                  const float* __restrict__ b2,
                                                  float* out) {
    __shared__ float a[16][DIM];    // h tile
    __shared__ float hid[16][DIM];  // relu(h@w1) chunk
    int t = threadIdx.x;
    int rg = t >> 6;   // wave id -> rows rg*4..rg*4+3 (wave-uniform)
    int lane = t & 63;
    int c0 = lane * 4;
    size_t row0 = (size_t)blockIdx.x * 16;
#pragma unroll 4
    for (int i = 0; i < 16; i++) a[i][t] = h[(row0 + i) * DIM + t];
    __syncthreads();

    float outacc[4][4] = {};
#pragma unroll 1
    for (int chunk = 0; chunk < 2; chunk++) {
        int cc = chunk * 256 + c0;
        float hidacc[4][4] = {};
        for (int kk = 0; kk < DIM; kk += 4) {
            float af[4][4];
#pragma unroll
            for (int i = 0; i < 4; i++) {
                float4 v = *(const float4*)&a[rg * 4 + i][kk];
                af[i][0] = v.x; af[i][1] = v.y; af[i][2] = v.z; af[i][3] = v.w;
            }
            float wf[4][4];
#pragma unroll
            for (int j2 = 0; j2 < 4; j2++) {
                float4 v = *(const float4*)&w1[(size_t)(kk + j2) * DFF + cc];
                wf[j2][0] = v.x; wf[j2][1] = v.y; wf[j2][2] = v.z; wf[j2][3] = v.w;
            }
#pragma unroll
            for (int i = 0; i < 4; i++)
#pragma unroll
                for (int j2 = 0; j2 < 4; j2++)
#pragma unroll
                    for (int j = 0; j < 4; j++)
                        hidacc[i][j] = fmaf(af[i][j2], wf[j2][j], hidacc[i][j]);
        }
        float4 b1v = *(const float4*)&b1[cc];
        float bb[4] = {b1v.x, b1v.y, b1v.z, b1v.w};
        __syncthreads();  // previous chunk's hid reads done
#pragma unroll
        for (int i = 0; i < 4; i++)
#pragma unroll
            for (int j = 0; j < 4; j++) {
                float v = hidacc[i][j] + bb[j];
                hid[rg * 4 + i][c0 + j] = v > 0.f ? v : 0.f;
            }
        __syncthreads();
        for (int jj = 0; jj < 256; jj += 4) {
            float hf[4][4];
#pragma unroll
            for (int i = 0; i < 4; i++) {
                float4 v = *(const float4*)&hid[rg * 4 + i][jj];
                hf[i][0] = v.x; hf[i][1] = v.y; hf[i][2] = v.z; hf[i][3] = v.w;
            }
            float wf[4][4];
#pragma unroll
            for (int j2 = 0; j2 < 4; j2++) {
                float4 v = *(const float4*)&w2[(size_t)(chunk * 256 + jj + j2) * DIM + c0];
                wf[j2][0] = v.x; wf[j2][1] = v.y; wf[j2][2] = v.z; wf[j2][3] = v.w;
            }
#pragma unroll
            for (int i = 0; i < 4; i++)
#pragma unroll
                for (int j2 = 0; j2 < 4; j2++)
#pragma unroll
                    for (int j = 0; j < 4; j++)
                        outacc[i][j] = fmaf(hf[i][j2], wf[j2][j], outacc[i][j]);
        }
    }
    float4 b2v = *(const float4*)&b2[c0];
    float bb2[4] = {b2v.x, b2v.y, b2v.z, b2v.w};
#pragma unroll
    for (int i = 0; i < 4; i++)
#pragma unroll
        for (int j = 0; j < 4; j++)
            out[(row0 + rg * 4 + i) * DIM + c0 + j] = outacc[i][j] + bb2[j];
}

// ---------------- launch ----------------
extern "C" void kernel_launch(void* const* d_in, const int* in_sizes, int n_in,
                              void* d_out, int out_size, void* d_ws, size_t ws_size,
                              hipStream_t stream) {
    const float* word   = (const float*)d_in[0];
    const float* sent   = (const float*)d_in[1];
    const int*   src    = (const int*)d_in[2];
    const int*   dst    = (const int*)d_in[3];
    const float* W_src  = (const float*)d_in[4];
    const float* W_dst  = (const float*)d_in[5];
    const float* attn_l = (const float*)d_in[6];
    const float* attn_r = (const float*)d_in[7];
    const float* gbias  = (const float*)d_in[8];
    const float* w1     = (const float*)d_in[9];
    const float* b1     = (const float*)d_in[10];
    const float* w2     = (const float*)d_in[11];
    const float* b2     = (const float*)d_in[12];
    float* out = (float*)d_out;

    float* ws       = (float*)d_ws;
    float* el       = ws;                              // NS*4
    float* er       = el + (size_t)NS * NH;            // NW*4
    float* C_src    = er + (size_t)NW * NH;            // 1024
    float* C_dst    = C_src + DIM * NH;                // 1024
    float* feat_src = C_dst + DIM * NH;                // NS*256
    int*   count    = (int*)(feat_src + (size_t)NS * DIM);  // NW
    int*   bucket   = count + NW;                      // NW*CAP

    hipLaunchKernelGGL(zero_count, dim3((NW + 255) / 256), dim3(256), 0, stream, count);
    hipLaunchKernelGGL(compute_C, dim3(2), dim3(256), 0, stream,
                       W_src, attn_l, W_dst, attn_r, C_src, C_dst);
    hipLaunchKernelGGL(rowdot, dim3(NS / 4), dim3(256), 0, stream, sent, C_src, el, NS);
    hipLaunchKernelGGL(rowdot, dim3(NW / 4), dim3(256), 0, stream, word, C_dst, er, NW);
    hipLaunchKernelGGL(feat_gemm, dim3(NS / 16), dim3(256), 0, stream, sent, W_src, feat_src);
    hipLaunchKernelGGL(scatter_edges, dim3(NE / 256), dim3(256), 0, stream, src, dst, count, bucket);
    hipLaunchKernelGGL(gat_aggregate, dim3(NW / 4), dim3(256), 0, stream,
                       count, bucket, el, er, feat_src, word, gbias, out);
    hipLaunchKernelGGL(ffn_kernel, dim3(NW / 16), dim3(256), 0, stream, out, w1, b1, w2, b2, out);
}

// Round 2
// 624.718 us; speedup vs baseline: 1.9513x; 1.9513x over previous
//
#include <hip/hip_runtime.h>
#include <math.h>

#define NW 100000
#define NS 10000
#define NE 800000
#define DIM 256
#define NH 4
#define DHD 64
#define DFF 512
#define NEG_SLOPE 0.2f
#define CAP 64   // bucket capacity per word node; deg ~ Poisson(8), P(>64) ~ 0

typedef __attribute__((ext_vector_type(8))) short bf16x8;
typedef __attribute__((ext_vector_type(8))) unsigned short ushortx8;
typedef __attribute__((ext_vector_type(4))) float floatx4;

// ---------------- helpers ----------------
__device__ __forceinline__ float wave_max64(float v) {
#pragma unroll
    for (int m = 32; m; m >>= 1) v = fmaxf(v, __shfl_xor(v, m, 64));
    return v;
}
__device__ __forceinline__ float wave_sum64(float v) {
#pragma unroll
    for (int m = 32; m; m >>= 1) v += __shfl_xor(v, m, 64);
    return v;
}
__device__ __forceinline__ unsigned short f2bf(float f) {  // RNE fp32->bf16
    unsigned int u = __float_as_uint(f);
    unsigned int r = (u + 0x7fffu + ((u >> 16) & 1u)) >> 16;
    return (unsigned short)r;
}
__device__ __forceinline__ void gload_lds16(const void* g, void* l) {
    __builtin_amdgcn_global_load_lds(
        (const __attribute__((address_space(1))) unsigned int*)g,
        (__attribute__((address_space(3))) unsigned int*)l, 16, 0, 0);
}

// ---------------- small kernels (unchanged structure) ----------------

__global__ void zero_count(int* __restrict__ count) {
    int i = blockIdx.x * 256 + threadIdx.x;
    if (i < NW) count[i] = 0;
}

__global__ void compute_C(const float* __restrict__ W_src, const float* __restrict__ attn_l,
                          const float* __restrict__ W_dst, const float* __restrict__ attn_r,
                          float* __restrict__ C_src, float* __restrict__ C_dst) {
    const float* W = blockIdx.x ? W_dst : W_src;
    const float* A = blockIdx.x ? attn_r : attn_l;
    float* C = blockIdx.x ? C_dst : C_src;
    int k = threadIdx.x;
#pragma unroll
    for (int h = 0; h < NH; h++) {
        float s = 0.f;
        for (int d = 0; d < DHD; d++) s += W[k * DIM + h * DHD + d] * A[h * DHD + d];
        C[k * NH + h] = s;
    }
}

__global__ __launch_bounds__(256) void rowdot(const float* __restrict__ X,
                                              const float* __restrict__ C,
                                              float* __restrict__ out, int N) {
    int wave = (blockIdx.x * blockDim.x + threadIdx.x) >> 6;
    int lane = threadIdx.x & 63;
    if (wave >= N) return;
    float4 x = ((const float4*)(X + (size_t)wave * DIM))[lane];
    const float4* Cv = (const float4*)C;
    float4 c0 = Cv[lane * 4 + 0], c1 = Cv[lane * 4 + 1], c2 = Cv[lane * 4 + 2], c3 = Cv[lane * 4 + 3];
    float p0 = x.x * c0.x + x.y * c1.x + x.z * c2.x + x.w * c3.x;
    float p1 = x.x * c0.y + x.y * c1.y + x.z * c2.y + x.w * c3.y;
    float p2 = x.x * c0.z + x.y * c1.z + x.z * c2.z + x.w * c3.z;
    float p3 = x.x * c0.w + x.y * c1.w + x.z * c2.w + x.w * c3.w;
    p0 = wave_sum64(p0); p1 = wave_sum64(p1); p2 = wave_sum64(p2); p3 = wave_sum64(p3);
    if (lane == 0) {
        out[(size_t)wave * NH + 0] = p0; out[(size_t)wave * NH + 1] = p1;
        out[(size_t)wave * NH + 2] = p2; out[(size_t)wave * NH + 3] = p3;
    }
}

// feat_src = sent @ W_src (fp32, small: 1.3 GF)
__global__ __launch_bounds__(256) void feat_gemm(const float* __restrict__ X,
                                                 const float* __restrict__ W,
                                                 float* __restrict__ out) {
    __shared__ float a[16][DIM];
    int t = threadIdx.x;
    int rg = t >> 6;
    int lane = t & 63;
    int c0 = lane * 4;
    size_t row0 = (size_t)blockIdx.x * 16;
#pragma unroll 4
    for (int i = 0; i < 16; i++) a[i][t] = X[(row0 + i) * DIM + t];
    __syncthreads();
    float acc[4][4] = {};
    for (int kk = 0; kk < DIM; kk += 4) {
        float af[4][4];
#pragma unroll
        for (int i = 0; i < 4; i++) {
            float4 v = *(const float4*)&a[rg * 4 + i][kk];
            af[i][0] = v.x; af[i][1] = v.y; af[i][2] = v.z; af[i][3] = v.w;
        }
        float wf[4][4];
#pragma unroll
        for (int j2 = 0; j2 < 4; j2++) {
            float4 v = *(const float4*)&W[(size_t)(kk + j2) * DIM + c0];
            wf[j2][0] = v.x; wf[j2][1] = v.y; wf[j2][2] = v.z; wf[j2][3] = v.w;
        }
#pragma unroll
        for (int i = 0; i < 4; i++)
#pragma unroll
            for (int j2 = 0; j2 < 4; j2++)
#pragma unroll
                for (int j = 0; j < 4; j++)
                    acc[i][j] = fmaf(af[i][j2], wf[j2][j], acc[i][j]);
    }
#pragma unroll
    for (int i = 0; i < 4; i++)
#pragma unroll
        for (int j = 0; j < 4; j++)
            out[(row0 + rg * 4 + i) * DIM + c0 + j] = acc[i][j];
}

__global__ void scatter_edges(const int* __restrict__ src, const int* __restrict__ dst,
                              int* __restrict__ count, unsigned short* __restrict__ bucket) {
    int e = blockIdx.x * 256 + threadIdx.x;
    if (e >= NE) return;
    int w = dst[e];
    int pos = atomicAdd(&count[w], 1);
    if (pos < CAP) bucket[(size_t)w * CAP + pos] = (unsigned short)src[e];
}

// one wave per word node: edge softmax + weighted gather + elu + residual -> h (fp32, d_out)
__global__ __launch_bounds__(256) void gat_aggregate(const int* __restrict__ count,
                                                     const unsigned short* __restrict__ bucket,
                                                     const float* __restrict__ el,
                                                     const float* __restrict__ er,
                                                     const float* __restrict__ feat_src,
                                                     const float* __restrict__ word,
                                                     const float* __restrict__ gat_bias,
                                                     float* __restrict__ h_out) {
    int node = blockIdx.x * 4 + (threadIdx.x >> 6);
    int lane = threadIdx.x & 63;
    if (node >= NW) return;
    int deg = count[node];
    if (deg > CAP) deg = CAP;

    float er0 = er[(size_t)node * NH + 0];
    float er1 = er[(size_t)node * NH + 1];
    float er2 = er[(size_t)node * NH + 2];
    float er3 = er[(size_t)node * NH + 3];

    int s = 0;
    float e0 = -3.4e38f, e1 = -3.4e38f, e2 = -3.4e38f, e3 = -3.4e38f;
    if (lane < deg) {
        s = bucket[(size_t)node * CAP + lane];
        float v;
        v = el[(size_t)s * NH + 0] + er0; e0 = v > 0.f ? v : NEG_SLOPE * v;
        v = el[(size_t)s * NH + 1] + er1; e1 = v > 0.f ? v : NEG_SLOPE * v;
        v = el[(size_t)s * NH + 2] + er2; e2 = v > 0.f ? v : NEG_SLOPE * v;
        v = el[(size_t)s * NH + 3] + er3; e3 = v > 0.f ? v : NEG_SLOPE * v;
    }
    float m0 = wave_max64(e0), m1 = wave_max64(e1), m2 = wave_max64(e2), m3 = wave_max64(e3);
    float x0 = lane < deg ? expf(e0 - m0) : 0.f;
    float x1 = lane < deg ? expf(e1 - m1) : 0.f;
    float x2 = lane < deg ? expf(e2 - m2) : 0.f;
    float x3 = lane < deg ? expf(e3 - m3) : 0.f;
    float d0 = wave_sum64(x0), d1 = wave_sum64(x1), d2 = wave_sum64(x2), d3 = wave_sum64(x3);
    float a0 = x0 / d0, a1 = x1 / d1, a2 = x2 / d2, a3 = x3 / d3;

    int hh = lane >> 4;
    float4 acc = {0.f, 0.f, 0.f, 0.f};
    for (int i = 0; i < deg; i++) {
        int si = __shfl(s, i, 64);
        float b0 = __shfl(a0, i, 64), b1 = __shfl(a1, i, 64);
        float b2 = __shfl(a2, i, 64), b3 = __shfl(a3, i, 64);
        float aa = hh == 0 ? b0 : hh == 1 ? b1 : hh == 2 ? b2 : b3;
        float4 f = ((const float4*)(feat_src + (size_t)si * DIM))[lane];
        acc.x = fmaf(aa, f.x, acc.x);
        acc.y = fmaf(aa, f.y, acc.y);
        acc.z = fmaf(aa, f.z, acc.z);
        acc.w = fmaf(aa, f.w, acc.w);
    }
    float4 bias = ((const float4*)gat_bias)[lane];
    float4 w = ((const float4*)(word + (size_t)node * DIM))[lane];
    float r0 = acc.x + bias.x; r0 = r0 > 0.f ? r0 : (expf(r0) - 1.f);
    float r1 = acc.y + bias.y; r1 = r1 > 0.f ? r1 : (expf(r1) - 1.f);
    float r2 = acc.z + bias.z; r2 = r2 > 0.f ? r2 : (expf(r2) - 1.f);
    float r3 = acc.w + bias.w; r3 = r3 > 0.f ? r3 : (expf(r3) - 1.f);
    float4 o;
    o.x = w.x + r0; o.y = w.y + r1; o.z = w.z + r2; o.w = w.w + r3;
    ((float4*)(h_out + (size_t)node * DIM))[lane] = o;
}

// ---------------- FFN via bf16 MFMA ----------------

// transpose + convert weights: w1t[n][k]=bf16(w1[k][n]) (512x256), w2t[n][k]=bf16(w2[k][n]) (256x512)
__global__ void prep_weights(const float* __restrict__ w1, const float* __restrict__ w2,
                             unsigned short* __restrict__ w1t, unsigned short* __restrict__ w2t) {
    int b = blockIdx.x, t = threadIdx.x;
    if (b < DFF) {
        w1t[(size_t)b * 256 + t] = f2bf(w1[(size_t)t * DFF + b]);
    } else {
        int n = b - DFF;
        w2t[(size_t)n * DFF + t]       = f2bf(w2[(size_t)t * 256 + n]);
        w2t[(size_t)n * DFF + t + 256] = f2bf(w2[(size_t)(t + 256) * 256 + n]);
    }
}

// GEMM1: hid = relu(h @ w1 + b1) in bf16. h fp32 [rows,256] (slab of d_out),
// w1t bf16 [512,256] (K-contiguous). Block tile 128(M)x128(N), K chunked by 64.
// LDS granule = 16B (8 bf16); slot s of row r holds global granule s^(r&7) (XOR swizzle).
__global__ __launch_bounds__(256) void gemm1_mfma(const float* __restrict__ h,
                                                  const unsigned short* __restrict__ w1t,
                                                  const float* __restrict__ b1,
                                                  unsigned short* __restrict__ hid,
                                                  int slab0, int valid) {
    __shared__ unsigned short As[128 * 64];
    __shared__ unsigned short Bs[128 * 64];
    int tid = threadIdx.x;
    int lane = tid & 63;
    int wv = tid >> 6;
    int wm = wv >> 1, wn = wv & 1;
    int quad = lane >> 4, l15 = lane & 15;
    int mrow0 = blockIdx.x * 128;
    int n0g = blockIdx.y * 128;
    floatx4 acc[4][4];
#pragma unroll
    for (int i = 0; i < 4; i++)
#pragma unroll
        for (int j = 0; j < 4; j++) acc[i][j] = (floatx4){0.f, 0.f, 0.f, 0.f};

    for (int kc = 0; kc < 4; kc++) {
        if (kc) __syncthreads();
        // stage A: fp32 -> bf16, thread = one 16B granule per iter
#pragma unroll
        for (int it = 0; it < 4; it++) {
            int gid = it * 256 + tid;
            int r = gid >> 3, gl = gid & 7;
            int rl = mrow0 + r; rl = rl < valid ? rl : valid - 1;
            const float* gp = h + (size_t)(slab0 + rl) * 256 + kc * 64 + gl * 8;
            float4 v0 = *(const float4*)gp;
            float4 v1 = *(const float4*)(gp + 4);
            ushortx8 pk;
            pk[0] = f2bf(v0.x); pk[1] = f2bf(v0.y); pk[2] = f2bf(v0.z); pk[3] = f2bf(v0.w);
            pk[4] = f2bf(v1.x); pk[5] = f2bf(v1.y); pk[6] = f2bf(v1.z); pk[7] = f2bf(v1.w);
            *(ushortx8*)&As[r * 64 + (gl ^ (r & 7)) * 8] = pk;
        }
        // stage B via global_load_lds (lane permute implements the swizzle)
#pragma unroll
        for (int it = 0; it < 4; it++) {
            int rbase = wv * 32 + it * 8;
            int r = rbase + (lane >> 3);
            int glf = (lane & 7) ^ (r & 7);
            const unsigned short* gp = w1t + (size_t)(n0g + r) * 256 + kc * 64 + glf * 8;
            gload_lds16(gp, &Bs[rbase * 64]);
        }
        __syncthreads();
#pragma unroll
        for (int s = 0; s < 2; s++) {
            bf16x8 a[4], b[4];
#pragma unroll
            for (int mt = 0; mt < 4; mt++) {
                int r = wm * 64 + mt * 16 + l15;
                a[mt] = *(const bf16x8*)&As[r * 64 + (((s * 4 + quad) ^ (r & 7)) * 8)];
            }
#pragma unroll
            for (int nt = 0; nt < 4; nt++) {
                int r = wn * 64 + nt * 16 + l15;
                b[nt] = *(const bf16x8*)&Bs[r * 64 + (((s * 4 + quad) ^ (r & 7)) * 8)];
            }
#pragma unroll
            for (int mt = 0; mt < 4; mt++)
#pragma unroll
                for (int nt = 0; nt < 4; nt++)
                    acc[mt][nt] = __builtin_amdgcn_mfma_f32_16x16x32_bf16(a[mt], b[nt], acc[mt][nt], 0, 0, 0);
        }
    }
    // epilogue: bias + relu + cvt; C layout col=lane&15, row=quad*4+reg
#pragma unroll
    for (int nt = 0; nt < 4; nt++) {
        int c = n0g + wn * 64 + nt * 16 + l15;
        float bias = b1[c];
#pragma unroll
        for (int mt = 0; mt < 4; mt++) {
            int rbase = mrow0 + wm * 64 + mt * 16 + quad * 4;
#pragma unroll
            for (int i = 0; i < 4; i++) {
                int rl = rbase + i;
                if (rl < valid) {
                    float v = acc[mt][nt][i] + bias;
                    v = v > 0.f ? v : 0.f;
                    hid[(size_t)rl * DFF + c] = f2bf(v);
                }
            }
        }
    }
}

// GEMM2: out = hid @ w2 + b2. hid bf16 [rows,512], w2t bf16 [256,512]. Writes fp32 d_out.
__global__ __launch_bounds__(256) void gemm2_mfma(const unsigned short* __restrict__ hid,
                                                  const unsigned short* __restrict__ w2t,
                                                  const float* __restrict__ b2,
                                                  float* __restrict__ out,
                                                  int slab0, int valid) {
    __shared__ unsigned short As[128 * 64];
    __shared__ unsigned short Bs[128 * 64];
    int tid = threadIdx.x;
    int lane = tid & 63;
    int wv = tid >> 6;
    int wm = wv >> 1, wn = wv & 1;
    int quad = lane >> 4, l15 = lane & 15;
    int mrow0 = blockIdx.x * 128;
    int n0g = blockIdx.y * 128;
    floatx4 acc[4][4];
#pragma unroll
    for (int i = 0; i < 4; i++)
#pragma unroll
        for (int j = 0; j < 4; j++) acc[i][j] = (floatx4){0.f, 0.f, 0.f, 0.f};

    for (int kc = 0; kc < 8; kc++) {
        if (kc) __syncthreads();
#pragma unroll
        for (int it = 0; it < 4; it++) {   // stage A (hid, bf16)
            int rbase = wv * 32 + it * 8;
            int r = rbase + (lane >> 3);
            int rl = mrow0 + r; rl = rl < valid ? rl : valid - 1;
            int glf = (lane & 7) ^ (r & 7);
            const unsigned short* gp = hid + (size_t)rl * DFF + kc * 64 + glf * 8;
            gload_lds16(gp, &As[rbase * 64]);
        }
#pragma unroll
        for (int it = 0; it < 4; it++) {   // stage B (w2t)
            int rbase = wv * 32 + it * 8;
            int r = rbase + (lane >> 3);
            int glf = (lane & 7) ^ (r & 7);
            const unsigned short* gp = w2t + (size_t)(n0g + r) * DFF + kc * 64 + glf * 8;
            gload_lds16(gp, &Bs[rbase * 64]);
        }
        __syncthreads();
#pragma unroll
        for (int s = 0; s < 2; s++) {
            bf16x8 a[4], b[4];
#pragma unroll
            for (int mt = 0; mt < 4; mt++) {
                int r = wm * 64 + mt * 16 + l15;
                a[mt] = *(const bf16x8*)&As[r * 64 + (((s * 4 + quad) ^ (r & 7)) * 8)];
            }
#pragma unroll
            for (int nt = 0; nt < 4; nt++) {
                int r = wn * 64 + nt * 16 + l15;
                b[nt] = *(const bf16x8*)&Bs[r * 64 + (((s * 4 + quad) ^ (r & 7)) * 8)];
            }
#pragma unroll
            for (int mt = 0; mt < 4; mt++)
#pragma unroll
                for (int nt = 0; nt < 4; nt++)
                    acc[mt][nt] = __builtin_amdgcn_mfma_f32_16x16x32_bf16(a[mt], b[nt], acc[mt][nt], 0, 0, 0);
        }
    }
#pragma unroll
    for (int nt = 0; nt < 4; nt++) {
        int c = n0g + wn * 64 + nt * 16 + l15;
        float bias = b2[c];
#pragma unroll
        for (int mt = 0; mt < 4; mt++) {
            int rbase = mrow0 + wm * 64 + mt * 16 + quad * 4;
#pragma unroll
            for (int i = 0; i < 4; i++) {
                int rl = rbase + i;
                if (rl < valid)
                    out[(size_t)(slab0 + rl) * 256 + c] = acc[mt][nt][i] + bias;
            }
        }
    }
}

// ---------------- launch ----------------
extern "C" void kernel_launch(void* const* d_in, const int* in_sizes, int n_in,
                              void* d_out, int out_size, void* d_ws, size_t ws_size,
                              hipStream_t stream) {
    const float* word   = (const float*)d_in[0];
    const float* sent   = (const float*)d_in[1];
    const int*   src    = (const int*)d_in[2];
    const int*   dst    = (const int*)d_in[3];
    const float* W_src  = (const float*)d_in[4];
    const float* W_dst  = (const float*)d_in[5];
    const float* attn_l = (const float*)d_in[6];
    const float* attn_r = (const float*)d_in[7];
    const float* gbias  = (const float*)d_in[8];
    const float* w1     = (const float*)d_in[9];
    const float* b1     = (const float*)d_in[10];
    const float* w2     = (const float*)d_in[11];
    const float* b2     = (const float*)d_in[12];
    float* out = (float*)d_out;

    char* wsb = (char*)d_ws;
    unsigned short* w1t = (unsigned short*)wsb;                  // 512*256
    unsigned short* w2t = w1t + (size_t)DFF * 256;               // 256*512
    char* R = (char*)(w2t + (size_t)256 * DFF);                  // reusable region
    // phase-1 layout inside R
    float* el       = (float*)R;                                 // NS*4
    float* er       = el + (size_t)NS * NH;                      // NW*4
    float* C_src    = er + (size_t)NW * NH;
    float* C_dst    = C_src + DIM * NH;
    float* feat_src = C_dst + DIM * NH;                          // NS*256
    int*   count    = (int*)(feat_src + (size_t)NS * DIM);       // NW
    unsigned short* bucket = (unsigned short*)(count + NW);      // NW*CAP
    // phase-2: hid reuses R
    unsigned short* hid = (unsigned short*)R;
    size_t Rbytes = ws_size - (size_t)(R - wsb);
    size_t slab_rows = Rbytes / ((size_t)DFF * 2);
    if (slab_rows > NW) slab_rows = NW;
    slab_rows &= ~(size_t)127;  // multiple of 128

    hipLaunchKernelGGL(zero_count, dim3((NW + 255) / 256), dim3(256), 0, stream, count);
    hipLaunchKernelGGL(compute_C, dim3(2), dim3(256), 0, stream,
                       W_src, attn_l, W_dst, attn_r, C_src, C_dst);
    hipLaunchKernelGGL(prep_weights, dim3(DFF + 256), dim3(256), 0, stream, w1, w2, w1t, w2t);
    hipLaunchKernelGGL(rowdot, dim3(NS / 4), dim3(256), 0, stream, sent, C_src, el, NS);
    hipLaunchKernelGGL(rowdot, dim3(NW / 4), dim3(256), 0, stream, word, C_dst, er, NW);
    hipLaunchKernelGGL(feat_gemm, dim3(NS / 16), dim3(256), 0, stream, sent, W_src, feat_src);
    hipLaunchKernelGGL(scatter_edges, dim3(NE / 256), dim3(256), 0, stream, src, dst, count, bucket);
    hipLaunchKernelGGL(gat_aggregate, dim3(NW / 4), dim3(256), 0, stream,
                       count, bucket, el, er, feat_src, word, gbias, out);

    size_t done = 0;
    while (done < NW) {
        size_t valid = (size_t)NW - done;
        if (valid > slab_rows) valid = slab_rows;
        int gm = (int)((valid + 127) / 128);
        hipLaunchKernelGGL(gemm1_mfma, dim3(gm, 4), dim3(256), 0, stream,
                           out, w1t, b1, hid, (int)done, (int)valid);
        hipLaunchKernelGGL(gemm2_mfma, dim3(gm, 2), dim3(256), 0, stream,
                           hid, w2t, b2, out, (int)done, (int)valid);
        done += valid;
    }
}